// Round 12
// baseline (343.185 us; speedup 1.0000x reference)
//
#include <hip/hip_runtime.h>

#define F0 11
#define F1 128
#define F2 64

// ---------------- in-degree histogram ----------------
__global__ void k_count(const int* __restrict__ dst, int E, int* __restrict__ cnt) {
    int e = blockIdx.x * blockDim.x + threadIdx.x;
    if (e < E) atomicAdd(&cnt[dst[e]], 1);
}

// ---------------- exclusive scan of deg -> rowptr ----------------
__global__ void k_scanA(const int* __restrict__ deg, int* __restrict__ rowloc,
                        int* __restrict__ bsum, int N) {
    __shared__ int s[256];
    int i = blockIdx.x * 256 + threadIdx.x;
    int v = (i < N) ? deg[i] : 0;
    s[threadIdx.x] = v;
    __syncthreads();
    for (int o = 1; o < 256; o <<= 1) {
        int t = (threadIdx.x >= o) ? s[threadIdx.x - o] : 0;
        __syncthreads();
        s[threadIdx.x] += t;
        __syncthreads();
    }
    if (i < N) rowloc[i] = s[threadIdx.x] - v;
    if (threadIdx.x == 255) bsum[blockIdx.x] = s[255];
}

__global__ void k_scanB(int* __restrict__ bsum, int B) {
    __shared__ int s[256];
    int t = threadIdx.x;
    int v = (t < B) ? bsum[t] : 0;
    s[t] = v;
    __syncthreads();
    for (int o = 1; o < 256; o <<= 1) {
        int u = (t >= o) ? s[t - o] : 0;
        __syncthreads();
        s[t] += u;
        __syncthreads();
    }
    if (t < B) bsum[t] = s[t] - v;
}

// rowptr + cursor copy + dis
__global__ void k_scanC(const int* __restrict__ rowloc, const int* __restrict__ bsum,
                        const int* __restrict__ deg, int* __restrict__ rowptr,
                        int* __restrict__ cursor, float* __restrict__ dis, int N) {
    int i = blockIdx.x * 256 + threadIdx.x;
    if (i < N) {
        int r = rowloc[i] + bsum[blockIdx.x];
        rowptr[i] = r;
        cursor[i] = r;
        dis[i] = 1.0f / sqrtf((float)(deg[i] + 1));
    }
}

// ---------------- scatter edges into CSR: pack (src, dis[src]) ----------------
__global__ void k_scatter(const int* __restrict__ src, const int* __restrict__ dst,
                          const float* __restrict__ dis, int* __restrict__ cursor,
                          int2* __restrict__ epack, int E) {
    int e = blockIdx.x * blockDim.x + threadIdx.x;
    if (e >= E) return;
    int s = src[e], d = dst[e];
    int pos = atomicAdd(&cursor[d], 1);
    epack[pos] = make_int2(s, __float_as_int(dis[s]));
}

// ---------------- fused layer-1: CSR-aggregate raw x (11f) + @W1 + relu ----------------
__global__ void k_agg1l1(const int* __restrict__ rowptr, const int* __restrict__ deg,
                         const int2* __restrict__ epack, const float* __restrict__ x,
                         const float* __restrict__ dis, const float* __restrict__ W1,
                         const float* __restrict__ b1, float* __restrict__ h1, int N) {
    __shared__ float sW[F0 * F1];
    __shared__ float sb[F1];
    int t = threadIdx.x;
    for (int i = t; i < F0 * F1; i += 256) sW[i] = W1[i];
    if (t < F1) sb[t] = b1[t];
    __syncthreads();

    int wid = t >> 6, lane = t & 63;
    int n = blockIdx.x * 4 + wid;
    if (n >= N) return;

    int r0 = rowptr[n], r1 = r0 + deg[n];
    int eo = lane >> 4, f = lane & 15;

    float acc = 0.0f;
    int j = r0 + eo;
    for (; j + 4 < r1; j += 8) {
        int2 p = epack[j];
        int2 q = epack[j + 4];
        if (f < F0) {
            acc += x[p.x * F0 + f] * __int_as_float(p.y);
            acc += x[q.x * F0 + f] * __int_as_float(q.y);
        }
    }
    if (j < r1) {
        int2 p = epack[j];
        if (f < F0) acc += x[p.x * F0 + f] * __int_as_float(p.y);
    }
    acc += __shfl_xor(acc, 16, 64);
    acc += __shfl_xor(acc, 32, 64);

    float dn = dis[n];
    float afull = acc * dn;
    if (f < F0) afull += x[n * F0 + f] * dn * dn;  // self-loop

    float o1 = sb[lane], o2 = sb[lane + 64];
#pragma unroll
    for (int k = 0; k < F0; k++) {
        float ak = __shfl(afull, k, 64);
        o1 += ak * sW[k * F1 + lane];
        o2 += ak * sW[k * F1 + lane + 64];
    }
    h1[(size_t)n * F1 + lane]      = fmaxf(o1, 0.0f);
    h1[(size_t)n * F1 + lane + 64] = fmaxf(o2, 0.0f);
}

// ---------------- t2 = h1 @ W2 -> CHUNKED layout t2c[4][N][16] ----------------
__global__ void k_l2(const float* __restrict__ h1, const float* __restrict__ W2,
                     float* __restrict__ t2c, int N) {
    __shared__ float sW[F1 * F2];   // 32 KB
    __shared__ float sh[4][F1];
    int t = threadIdx.x;
    int grp = t >> 6, lane = t & 63;
    for (int i = t; i < F1 * F2; i += 256) sW[i] = W2[i];
    int n0 = blockIdx.x * 16;
    for (int r = 0; r < 4; r++) {
        int n = n0 + r * 4 + grp;
        __syncthreads();
        if (n < N) {
            sh[grp][lane]      = h1[(size_t)n * F1 + lane];
            sh[grp][lane + 64] = h1[(size_t)n * F1 + lane + 64];
        }
        __syncthreads();
        if (n < N) {
            float acc = 0.0f;
#pragma unroll
            for (int k = 0; k < F1; k++) acc += sh[grp][k] * sW[k * F2 + lane];
            // chunked store: pass = lane>>4, feature-in-chunk = lane&15
            t2c[((size_t)(lane >> 4) * N + n) * 16 + (lane & 15)] = acc;
        }
    }
}

// ---------------- layer-2 aggregate, ONE 16-feature chunk per launch ----------------
// Chunk = 3.2 MB -> fits per-XCD L2 -> gather becomes L2-hit latency.
// Wave = 4 edge-slots x 16 features; shfl-reduce across slots; slot 0 writes.
__global__ void k_agg2pool_c(const int* __restrict__ rowptr, const int* __restrict__ deg,
                             const int2* __restrict__ epack, const float* __restrict__ t2c,
                             const float* __restrict__ dis, const float* __restrict__ b2,
                             const int* __restrict__ batch, float* __restrict__ gsum,
                             float* __restrict__ gcnt, int N, int pass) {
    int t = threadIdx.x;
    int wid = t >> 6, lane = t & 63;
    int n = blockIdx.x * 4 + wid;
    if (n >= N) return;
    int slot = lane >> 4, f = lane & 15;
    const float* __restrict__ chunk = t2c + (size_t)pass * N * 16;

    int r0 = rowptr[n], r1 = r0 + deg[n];
    float acc = 0.0f;
    int j = r0 + slot;
    for (; j + 4 < r1; j += 8) {
        int2 p = epack[j];
        int2 q = epack[j + 4];
        acc += __int_as_float(p.y) * chunk[p.x * 16 + f];
        acc += __int_as_float(q.y) * chunk[q.x * 16 + f];
    }
    if (j < r1) {
        int2 p = epack[j];
        acc += __int_as_float(p.y) * chunk[p.x * 16 + f];
    }
    acc += __shfl_xor(acc, 16, 64);
    acc += __shfl_xor(acc, 32, 64);

    float dn = dis[n];
    float h2 = fmaxf(acc * dn + chunk[n * 16 + f] * dn * dn + b2[pass * 16 + f], 0.0f);
    int g = batch[n];
    if (slot == 0) atomicAdd(&gsum[(size_t)g * F2 + pass * 16 + f], h2);
    if (lane == 0 && pass == 0) atomicAdd(&gcnt[g], 1.0f);
}

// ---------------- per-graph MLP head ----------------
__global__ void k_head(const float* __restrict__ gsum, const float* __restrict__ gcnt,
                       const float* __restrict__ Wf1, const float* __restrict__ bf1,
                       const float* __restrict__ Wf2, const float* __restrict__ bf2,
                       const float* __restrict__ Wf3, const float* __restrict__ bf3,
                       float* __restrict__ out, int G) {
    __shared__ float sg[F2];
    __shared__ float sh1[F1];
    __shared__ float sh2[F2];
    int g = blockIdx.x, t = threadIdx.x;
    if (t < F2) {
        float c = fmaxf(gcnt[g], 1.0f);
        sg[t] = gsum[g * F2 + t] / c;
    }
    __syncthreads();
    {
        float a = bf1[t];
#pragma unroll 8
        for (int k = 0; k < F2; k++) a += sg[k] * Wf1[k * F1 + t];
        sh1[t] = fmaxf(a, 0.0f);
    }
    __syncthreads();
    if (t < F2) {
        float a = bf2[t];
#pragma unroll 8
        for (int k = 0; k < F1; k++) a += sh1[k] * Wf2[k * F2 + t];
        sh2[t] = fmaxf(a, 0.0f);
    }
    __syncthreads();
    if (t < F2) {
        float v = sh2[t] * Wf3[t];
        for (int off = 32; off > 0; off >>= 1) v += __shfl_down(v, off, 64);
        if (t == 0) out[g] = v + bf3[0];
    }
}

extern "C" void kernel_launch(void* const* d_in, const int* in_sizes, int n_in,
                              void* d_out, int out_size, void* d_ws, size_t ws_size,
                              hipStream_t stream) {
    const float* x     = (const float*)d_in[0];
    const int*   ei    = (const int*)d_in[1];
    const int*   batch = (const int*)d_in[2];
    const float* W1    = (const float*)d_in[3];
    const float* b1    = (const float*)d_in[4];
    const float* W2    = (const float*)d_in[5];
    const float* b2    = (const float*)d_in[6];
    const float* Wf1   = (const float*)d_in[7];
    const float* bf1   = (const float*)d_in[8];
    const float* Wf2   = (const float*)d_in[9];
    const float* bf2   = (const float*)d_in[10];
    const float* Wf3   = (const float*)d_in[11];
    const float* bf3   = (const float*)d_in[12];
    float* out = (float*)d_out;

    const int N = in_sizes[0] / F0;
    const int E = in_sizes[1] / 2;
    const int G = out_size;
    const int* src = ei;
    const int* dst = ei + E;

    size_t off = 0;
    auto carve = [&](size_t bytes) {
        void* p = (char*)d_ws + off;
        off += (bytes + 255) & ~(size_t)255;
        return p;
    };
    int*   deg    = (int*)  carve((size_t)N * 4);
    int*   rowloc = (int*)  carve((size_t)N * 4);
    int*   rowptr = (int*)  carve((size_t)N * 4);
    int*   cursor = (int*)  carve((size_t)N * 4);
    int*   bsum   = (int*)  carve(256 * 4);
    float* dis    = (float*)carve((size_t)N * 4);
    int2*  epack  = (int2*) carve((size_t)E * 8);
    float* h1     = (float*)carve((size_t)N * F1 * 4);
    float* t2c    = (float*)carve((size_t)N * F2 * 4);   // chunked [4][N][16]
    float* gsum   = (float*)carve((size_t)G * (F2 + 1) * 4);
    float* gcnt   = gsum + (size_t)G * F2;
    (void)ws_size; (void)n_in;

    const int NB = (N + 255) / 256;

    hipMemsetAsync(deg,  0, (size_t)N * 4, stream);
    hipMemsetAsync(gsum, 0, (size_t)G * (F2 + 1) * 4, stream);

    k_count  <<<(E + 255) / 256, 256, 0, stream>>>(dst, E, deg);
    k_scanA  <<<NB, 256, 0, stream>>>(deg, rowloc, bsum, N);
    k_scanB  <<<1, 256, 0, stream>>>(bsum, NB);
    k_scanC  <<<NB, 256, 0, stream>>>(rowloc, bsum, deg, rowptr, cursor, dis, N);
    k_scatter<<<(E + 255) / 256, 256, 0, stream>>>(src, dst, dis, cursor, epack, E);
    k_agg1l1 <<<(N + 3) / 4, 256, 0, stream>>>(rowptr, deg, epack, x, dis, W1, b1, h1, N);
    k_l2     <<<(N + 15) / 16, 256, 0, stream>>>(h1, W2, t2c, N);
    for (int p = 0; p < 4; p++)
        k_agg2pool_c<<<(N + 3) / 4, 256, 0, stream>>>(rowptr, deg, epack, t2c, dis, b2,
                                                      batch, gsum, gcnt, N, p);
    k_head   <<<G, F1, 0, stream>>>(gsum, gcnt, Wf1, bf1, Wf2, bf2, Wf3, bf3, out, G);
}

// Round 13
// 272.115 us; speedup vs baseline: 1.2612x; 1.2612x over previous
//
#include <hip/hip_runtime.h>

#define F0 11
#define F1 128
#define F2 64
#define TN 64   // nodes per k_l2gemm block tile

// ---------------- in-degree histogram ----------------
__global__ void k_count(const int* __restrict__ dst, int E, int* __restrict__ cnt) {
    int e = blockIdx.x * blockDim.x + threadIdx.x;
    if (e < E) atomicAdd(&cnt[dst[e]], 1);
}

// ---------------- exclusive scan of deg -> rowptr ----------------
__global__ void k_scanA(const int* __restrict__ deg, int* __restrict__ rowloc,
                        int* __restrict__ bsum, int N) {
    __shared__ int s[256];
    int i = blockIdx.x * 256 + threadIdx.x;
    int v = (i < N) ? deg[i] : 0;
    s[threadIdx.x] = v;
    __syncthreads();
    for (int o = 1; o < 256; o <<= 1) {
        int t = (threadIdx.x >= o) ? s[threadIdx.x - o] : 0;
        __syncthreads();
        s[threadIdx.x] += t;
        __syncthreads();
    }
    if (i < N) rowloc[i] = s[threadIdx.x] - v;
    if (threadIdx.x == 255) bsum[blockIdx.x] = s[255];
}

__global__ void k_scanB(int* __restrict__ bsum, int B) {
    __shared__ int s[256];
    int t = threadIdx.x;
    int v = (t < B) ? bsum[t] : 0;
    s[t] = v;
    __syncthreads();
    for (int o = 1; o < 256; o <<= 1) {
        int u = (t >= o) ? s[t - o] : 0;
        __syncthreads();
        s[t] += u;
        __syncthreads();
    }
    if (t < B) bsum[t] = s[t] - v;
}

// rowptr + cursor copy + dis
__global__ void k_scanC(const int* __restrict__ rowloc, const int* __restrict__ bsum,
                        const int* __restrict__ deg, int* __restrict__ rowptr,
                        int* __restrict__ cursor, float* __restrict__ dis, int N) {
    int i = blockIdx.x * 256 + threadIdx.x;
    if (i < N) {
        int r = rowloc[i] + bsum[blockIdx.x];
        rowptr[i] = r;
        cursor[i] = r;
        dis[i] = 1.0f / sqrtf((float)(deg[i] + 1));
    }
}

// ---------------- scatter edges into CSR: pack (src, dis[src]) ----------------
__global__ void k_scatter(const int* __restrict__ src, const int* __restrict__ dst,
                          const float* __restrict__ dis, int* __restrict__ cursor,
                          int2* __restrict__ epack, int E) {
    int e = blockIdx.x * blockDim.x + threadIdx.x;
    if (e >= E) return;
    int s = src[e], d = dst[e];
    int pos = atomicAdd(&cursor[d], 1);
    epack[pos] = make_int2(s, __float_as_int(dis[s]));
}

// ---------------- fused layer-1: CSR-aggregate raw x (11f) + @W1 + relu ----------------
__global__ void k_agg1l1(const int* __restrict__ rowptr, const int* __restrict__ deg,
                         const int2* __restrict__ epack, const float* __restrict__ x,
                         const float* __restrict__ dis, const float* __restrict__ W1,
                         const float* __restrict__ b1, float* __restrict__ h1, int N) {
    __shared__ float sW[F0 * F1];
    __shared__ float sb[F1];
    int t = threadIdx.x;
    for (int i = t; i < F0 * F1; i += 256) sW[i] = W1[i];
    if (t < F1) sb[t] = b1[t];
    __syncthreads();

    int wid = t >> 6, lane = t & 63;
    int n = blockIdx.x * 4 + wid;
    if (n >= N) return;

    int r0 = rowptr[n], r1 = r0 + deg[n];
    int eo = lane >> 4, f = lane & 15;

    float acc = 0.0f;
    int j = r0 + eo;
    for (; j + 4 < r1; j += 8) {
        int2 p = epack[j];
        int2 q = epack[j + 4];
        if (f < F0) {
            acc += x[p.x * F0 + f] * __int_as_float(p.y);
            acc += x[q.x * F0 + f] * __int_as_float(q.y);
        }
    }
    if (j < r1) {
        int2 p = epack[j];
        if (f < F0) acc += x[p.x * F0 + f] * __int_as_float(p.y);
    }
    acc += __shfl_xor(acc, 16, 64);
    acc += __shfl_xor(acc, 32, 64);

    float dn = dis[n];
    float afull = acc * dn;
    if (f < F0) afull += x[n * F0 + f] * dn * dn;  // self-loop

    float o1 = sb[lane], o2 = sb[lane + 64];
#pragma unroll
    for (int k = 0; k < F0; k++) {
        float ak = __shfl(afull, k, 64);
        o1 += ak * sW[k * F1 + lane];
        o2 += ak * sW[k * F1 + lane + 64];
    }
    h1[(size_t)n * F1 + lane]      = fmaxf(o1, 0.0f);
    h1[(size_t)n * F1 + lane + 64] = fmaxf(o2, 0.0f);
}

// ---------------- t2 = h1 @ W2 : register-tiled GEMM ----------------
// 64 nodes x 64 outs per block, 256 threads; thread = 4 nodes x 4 outs in regs.
// sHt transposed+padded so the 4-node read is one conflict-free ds_read_b128.
// Per k: 2 LDS vector reads serve 16 FMAs -> VALU-bound (vs 2 reads / 1 FMA before).
__global__ __launch_bounds__(256)
void k_l2gemm(const float* __restrict__ h1, const float* __restrict__ W2,
              float* __restrict__ t2, int N) {
    __shared__ float sW[F1 * F2];        // [k][o], 32 KB
    __shared__ float sHt[F1][TN + 4];    // [k][node], pad 4 -> 34.8 KB
    int t = threadIdx.x;
    for (int idx = t; idx < F1 * F2 / 4; idx += 256)
        ((float4*)sW)[idx] = ((const float4*)W2)[idx];
    int n0 = blockIdx.x * TN;
    int nn = min(TN, N - n0);
    for (int idx = t; idx < nn * (F1 / 4); idx += 256) {
        int r = idx >> 5;            // local node
        int q = idx & 31;            // k-quad
        float4 v = ((const float4*)(h1 + (size_t)(n0 + r) * F1))[q];
        sHt[4 * q + 0][r] = v.x;
        sHt[4 * q + 1][r] = v.y;
        sHt[4 * q + 2][r] = v.z;
        sHt[4 * q + 3][r] = v.w;
    }
    __syncthreads();

    int i = t >> 4, j = t & 15;      // nodes 4i..4i+3, outs 4j..4j+3
    float4 c0 = {0,0,0,0}, c1 = {0,0,0,0}, c2 = {0,0,0,0}, c3 = {0,0,0,0};
#pragma unroll 4
    for (int k = 0; k < F1; k++) {
        float4 b = ((const float4*)(sW + k * F2))[j];
        float4 a = *(const float4*)&sHt[k][4 * i];
        c0.x += a.x * b.x; c0.y += a.x * b.y; c0.z += a.x * b.z; c0.w += a.x * b.w;
        c1.x += a.y * b.x; c1.y += a.y * b.y; c1.z += a.y * b.z; c1.w += a.y * b.w;
        c2.x += a.z * b.x; c2.y += a.z * b.y; c2.z += a.z * b.z; c2.w += a.z * b.w;
        c3.x += a.w * b.x; c3.y += a.w * b.y; c3.z += a.w * b.z; c3.w += a.w * b.w;
    }
    int nb = n0 + 4 * i;
    if (nb + 0 < N) ((float4*)(t2 + (size_t)(nb + 0) * F2))[j] = c0;
    if (nb + 1 < N) ((float4*)(t2 + (size_t)(nb + 1) * F2))[j] = c1;
    if (nb + 2 < N) ((float4*)(t2 + (size_t)(nb + 2) * F2))[j] = c2;
    if (nb + 3 < N) ((float4*)(t2 + (size_t)(nb + 3) * F2))[j] = c3;
}

// ---------------- fused layer-2 aggregate (pipelined CSR gather) + relu + mean-pool ----------------
__global__ void k_agg2pool(const int* __restrict__ rowptr, const int* __restrict__ deg,
                           const int2* __restrict__ epack, const float* __restrict__ t2,
                           const float* __restrict__ dis, const float* __restrict__ b2,
                           const int* __restrict__ batch, float* __restrict__ gsum,
                           float* __restrict__ gcnt, int N) {
    int t = threadIdx.x;
    int wid = t >> 6, lane = t & 63;
    int n = blockIdx.x * 4 + wid;
    if (n >= N) return;

    int r0 = rowptr[n], r1 = r0 + deg[n];
    float a0 = 0.f, a1 = 0.f, a2 = 0.f, a3 = 0.f;
    int j = r0;
    if (r1 - r0 >= 4) {
        int2 p0 = epack[j], p1 = epack[j + 1], p2 = epack[j + 2], p3 = epack[j + 3];
        j += 4;
        while (j + 4 <= r1) {
            int2 q0 = epack[j], q1 = epack[j + 1], q2 = epack[j + 2], q3 = epack[j + 3];
            a0 += __int_as_float(p0.y) * t2[(size_t)p0.x * F2 + lane];
            a1 += __int_as_float(p1.y) * t2[(size_t)p1.x * F2 + lane];
            a2 += __int_as_float(p2.y) * t2[(size_t)p2.x * F2 + lane];
            a3 += __int_as_float(p3.y) * t2[(size_t)p3.x * F2 + lane];
            p0 = q0; p1 = q1; p2 = q2; p3 = q3;
            j += 4;
        }
        a0 += __int_as_float(p0.y) * t2[(size_t)p0.x * F2 + lane];
        a1 += __int_as_float(p1.y) * t2[(size_t)p1.x * F2 + lane];
        a2 += __int_as_float(p2.y) * t2[(size_t)p2.x * F2 + lane];
        a3 += __int_as_float(p3.y) * t2[(size_t)p3.x * F2 + lane];
    }
    for (; j < r1; j++) {
        int2 p = epack[j];
        a0 += __int_as_float(p.y) * t2[(size_t)p.x * F2 + lane];
    }
    float acc = (a0 + a1) + (a2 + a3);
    float dn = dis[n];
    float h2 = fmaxf(acc * dn + t2[(size_t)n * F2 + lane] * dn * dn + b2[lane], 0.0f);
    int g = batch[n];
    atomicAdd(&gsum[(size_t)g * F2 + lane], h2);
    if (lane == 0) atomicAdd(&gcnt[g], 1.0f);
}

// ---------------- per-graph MLP head ----------------
__global__ void k_head(const float* __restrict__ gsum, const float* __restrict__ gcnt,
                       const float* __restrict__ Wf1, const float* __restrict__ bf1,
                       const float* __restrict__ Wf2, const float* __restrict__ bf2,
                       const float* __restrict__ Wf3, const float* __restrict__ bf3,
                       float* __restrict__ out, int G) {
    __shared__ float sg[F2];
    __shared__ float sh1[F1];
    __shared__ float sh2[F2];
    int g = blockIdx.x, t = threadIdx.x;
    if (t < F2) {
        float c = fmaxf(gcnt[g], 1.0f);
        sg[t] = gsum[g * F2 + t] / c;
    }
    __syncthreads();
    {
        float a = bf1[t];
#pragma unroll 8
        for (int k = 0; k < F2; k++) a += sg[k] * Wf1[k * F1 + t];
        sh1[t] = fmaxf(a, 0.0f);
    }
    __syncthreads();
    if (t < F2) {
        float a = bf2[t];
#pragma unroll 8
        for (int k = 0; k < F1; k++) a += sh1[k] * Wf2[k * F2 + t];
        sh2[t] = fmaxf(a, 0.0f);
    }
    __syncthreads();
    if (t < F2) {
        float v = sh2[t] * Wf3[t];
        for (int off = 32; off > 0; off >>= 1) v += __shfl_down(v, off, 64);
        if (t == 0) out[g] = v + bf3[0];
    }
}

extern "C" void kernel_launch(void* const* d_in, const int* in_sizes, int n_in,
                              void* d_out, int out_size, void* d_ws, size_t ws_size,
                              hipStream_t stream) {
    const float* x     = (const float*)d_in[0];
    const int*   ei    = (const int*)d_in[1];
    const int*   batch = (const int*)d_in[2];
    const float* W1    = (const float*)d_in[3];
    const float* b1    = (const float*)d_in[4];
    const float* W2    = (const float*)d_in[5];
    const float* b2    = (const float*)d_in[6];
    const float* Wf1   = (const float*)d_in[7];
    const float* bf1   = (const float*)d_in[8];
    const float* Wf2   = (const float*)d_in[9];
    const float* bf2   = (const float*)d_in[10];
    const float* Wf3   = (const float*)d_in[11];
    const float* bf3   = (const float*)d_in[12];
    float* out = (float*)d_out;

    const int N = in_sizes[0] / F0;
    const int E = in_sizes[1] / 2;
    const int G = out_size;
    const int* src = ei;
    const int* dst = ei + E;

    size_t off = 0;
    auto carve = [&](size_t bytes) {
        void* p = (char*)d_ws + off;
        off += (bytes + 255) & ~(size_t)255;
        return p;
    };
    int*   deg    = (int*)  carve((size_t)N * 4);
    int*   rowloc = (int*)  carve((size_t)N * 4);
    int*   rowptr = (int*)  carve((size_t)N * 4);
    int*   cursor = (int*)  carve((size_t)N * 4);
    int*   bsum   = (int*)  carve(256 * 4);
    float* dis    = (float*)carve((size_t)N * 4);
    int2*  epack  = (int2*) carve((size_t)E * 8);
    float* h1     = (float*)carve((size_t)N * F1 * 4);
    float* t2     = (float*)carve((size_t)N * F2 * 4);
    float* gsum   = (float*)carve((size_t)G * (F2 + 1) * 4);
    float* gcnt   = gsum + (size_t)G * F2;
    (void)ws_size; (void)n_in;

    const int NB = (N + 255) / 256;

    hipMemsetAsync(deg,  0, (size_t)N * 4, stream);
    hipMemsetAsync(gsum, 0, (size_t)G * (F2 + 1) * 4, stream);

    k_count  <<<(E + 255) / 256, 256, 0, stream>>>(dst, E, deg);
    k_scanA  <<<NB, 256, 0, stream>>>(deg, rowloc, bsum, N);
    k_scanB  <<<1, 256, 0, stream>>>(bsum, NB);
    k_scanC  <<<NB, 256, 0, stream>>>(rowloc, bsum, deg, rowptr, cursor, dis, N);
    k_scatter<<<(E + 255) / 256, 256, 0, stream>>>(src, dst, dis, cursor, epack, E);
    k_agg1l1 <<<(N + 3) / 4, 256, 0, stream>>>(rowptr, deg, epack, x, dis, W1, b1, h1, N);
    k_l2gemm <<<(N + TN - 1) / TN, 256, 0, stream>>>(h1, W2, t2, N);
    k_agg2pool<<<(N + 3) / 4, 256, 0, stream>>>(rowptr, deg, epack, t2, dis, b2, batch, gsum, gcnt, N);
    k_head   <<<G, F1, 0, stream>>>(gsum, gcnt, Wf1, bf1, Wf2, bf2, Wf3, bf3, out, G);
}

// Round 14
// 269.010 us; speedup vs baseline: 1.2757x; 1.0115x over previous
//
#include <hip/hip_runtime.h>

#define F0 11
#define F1 128
#define F2 64
#define TN 64   // nodes per k_l2gemm block tile

// ---------------- in-degree histogram ----------------
__global__ void k_count(const int* __restrict__ dst, int E, int* __restrict__ cnt) {
    int e = blockIdx.x * blockDim.x + threadIdx.x;
    if (e < E) atomicAdd(&cnt[dst[e]], 1);
}

// ---------------- exclusive scan of deg -> rowptr ----------------
__global__ void k_scanA(const int* __restrict__ deg, int* __restrict__ rowloc,
                        int* __restrict__ bsum, int N) {
    __shared__ int s[256];
    int i = blockIdx.x * 256 + threadIdx.x;
    int v = (i < N) ? deg[i] : 0;
    s[threadIdx.x] = v;
    __syncthreads();
    for (int o = 1; o < 256; o <<= 1) {
        int t = (threadIdx.x >= o) ? s[threadIdx.x - o] : 0;
        __syncthreads();
        s[threadIdx.x] += t;
        __syncthreads();
    }
    if (i < N) rowloc[i] = s[threadIdx.x] - v;
    if (threadIdx.x == 255) bsum[blockIdx.x] = s[255];
}

__global__ void k_scanB(int* __restrict__ bsum, int B) {
    __shared__ int s[256];
    int t = threadIdx.x;
    int v = (t < B) ? bsum[t] : 0;
    s[t] = v;
    __syncthreads();
    for (int o = 1; o < 256; o <<= 1) {
        int u = (t >= o) ? s[t - o] : 0;
        __syncthreads();
        s[t] += u;
        __syncthreads();
    }
    if (t < B) bsum[t] = s[t] - v;
}

// rowptr + cursor copy + dis
__global__ void k_scanC(const int* __restrict__ rowloc, const int* __restrict__ bsum,
                        const int* __restrict__ deg, int* __restrict__ rowptr,
                        int* __restrict__ cursor, float* __restrict__ dis, int N) {
    int i = blockIdx.x * 256 + threadIdx.x;
    if (i < N) {
        int r = rowloc[i] + bsum[blockIdx.x];
        rowptr[i] = r;
        cursor[i] = r;
        dis[i] = 1.0f / sqrtf((float)(deg[i] + 1));
    }
}

// ---------------- scatter edges into CSR: pack (src, dis[src]) ----------------
__global__ void k_scatter(const int* __restrict__ src, const int* __restrict__ dst,
                          const float* __restrict__ dis, int* __restrict__ cursor,
                          int2* __restrict__ epack, int E) {
    int e = blockIdx.x * blockDim.x + threadIdx.x;
    if (e >= E) return;
    int s = src[e], d = dst[e];
    int pos = atomicAdd(&cursor[d], 1);
    epack[pos] = make_int2(s, __float_as_int(dis[s]));
}

// ---------------- fused layer-1: CSR-aggregate raw x (11f) + @W1 + relu ----------------
__global__ void k_agg1l1(const int* __restrict__ rowptr, const int* __restrict__ deg,
                         const int2* __restrict__ epack, const float* __restrict__ x,
                         const float* __restrict__ dis, const float* __restrict__ W1,
                         const float* __restrict__ b1, float* __restrict__ h1, int N) {
    __shared__ float sW[F0 * F1];
    __shared__ float sb[F1];
    int t = threadIdx.x;
    for (int i = t; i < F0 * F1; i += 256) sW[i] = W1[i];
    if (t < F1) sb[t] = b1[t];
    __syncthreads();

    int wid = t >> 6, lane = t & 63;
    int n = blockIdx.x * 4 + wid;
    if (n >= N) return;

    int r0 = rowptr[n], r1 = r0 + deg[n];
    int eo = lane >> 4, f = lane & 15;

    float acc = 0.0f;
    int j = r0 + eo;
    for (; j + 4 < r1; j += 8) {
        int2 p = epack[j];
        int2 q = epack[j + 4];
        if (f < F0) {
            acc += x[p.x * F0 + f] * __int_as_float(p.y);
            acc += x[q.x * F0 + f] * __int_as_float(q.y);
        }
    }
    if (j < r1) {
        int2 p = epack[j];
        if (f < F0) acc += x[p.x * F0 + f] * __int_as_float(p.y);
    }
    acc += __shfl_xor(acc, 16, 64);
    acc += __shfl_xor(acc, 32, 64);

    float dn = dis[n];
    float afull = acc * dn;
    if (f < F0) afull += x[n * F0 + f] * dn * dn;  // self-loop

    float o1 = sb[lane], o2 = sb[lane + 64];
#pragma unroll
    for (int k = 0; k < F0; k++) {
        float ak = __shfl(afull, k, 64);
        o1 += ak * sW[k * F1 + lane];
        o2 += ak * sW[k * F1 + lane + 64];
    }
    h1[(size_t)n * F1 + lane]      = fmaxf(o1, 0.0f);
    h1[(size_t)n * F1 + lane + 64] = fmaxf(o2, 0.0f);
}

// ---------------- t2 = h1 @ W2 : register-tiled GEMM ----------------
__global__ __launch_bounds__(256)
void k_l2gemm(const float* __restrict__ h1, const float* __restrict__ W2,
              float* __restrict__ t2, int N) {
    __shared__ float sW[F1 * F2];        // [k][o], 32 KB
    __shared__ float sHt[F1][TN + 4];    // [k][node], pad 4 -> 34.8 KB
    int t = threadIdx.x;
    for (int idx = t; idx < F1 * F2 / 4; idx += 256)
        ((float4*)sW)[idx] = ((const float4*)W2)[idx];
    int n0 = blockIdx.x * TN;
    int nn = min(TN, N - n0);
    for (int idx = t; idx < nn * (F1 / 4); idx += 256) {
        int r = idx >> 5;            // local node
        int q = idx & 31;            // k-quad
        float4 v = ((const float4*)(h1 + (size_t)(n0 + r) * F1))[q];
        sHt[4 * q + 0][r] = v.x;
        sHt[4 * q + 1][r] = v.y;
        sHt[4 * q + 2][r] = v.z;
        sHt[4 * q + 3][r] = v.w;
    }
    __syncthreads();

    int i = t >> 4, j = t & 15;      // nodes 4i..4i+3, outs 4j..4j+3
    float4 c0 = {0,0,0,0}, c1 = {0,0,0,0}, c2 = {0,0,0,0}, c3 = {0,0,0,0};
#pragma unroll 4
    for (int k = 0; k < F1; k++) {
        float4 b = ((const float4*)(sW + k * F2))[j];
        float4 a = *(const float4*)&sHt[k][4 * i];
        c0.x += a.x * b.x; c0.y += a.x * b.y; c0.z += a.x * b.z; c0.w += a.x * b.w;
        c1.x += a.y * b.x; c1.y += a.y * b.y; c1.z += a.y * b.z; c1.w += a.y * b.w;
        c2.x += a.z * b.x; c2.y += a.z * b.y; c2.z += a.z * b.z; c2.w += a.z * b.w;
        c3.x += a.w * b.x; c3.y += a.w * b.y; c3.z += a.w * b.z; c3.w += a.w * b.w;
    }
    int nb = n0 + 4 * i;
    if (nb + 0 < N) ((float4*)(t2 + (size_t)(nb + 0) * F2))[j] = c0;
    if (nb + 1 < N) ((float4*)(t2 + (size_t)(nb + 1) * F2))[j] = c1;
    if (nb + 2 < N) ((float4*)(t2 + (size_t)(nb + 2) * F2))[j] = c2;
    if (nb + 3 < N) ((float4*)(t2 + (size_t)(nb + 3) * F2))[j] = c3;
}

// ---------------- fused layer-2 aggregate + relu + mean-pool ----------------
// Deepened pipeline: t2 VALUES prefetched one 4-group ahead, epack descriptors
// two groups ahead. Gather-wait overlaps the previous group's FMAs.
__global__ void k_agg2pool(const int* __restrict__ rowptr, const int* __restrict__ deg,
                           const int2* __restrict__ epack, const float* __restrict__ t2,
                           const float* __restrict__ dis, const float* __restrict__ b2,
                           const int* __restrict__ batch, float* __restrict__ gsum,
                           float* __restrict__ gcnt, int N) {
    int t = threadIdx.x;
    int wid = t >> 6, lane = t & 63;
    int n = blockIdx.x * 4 + wid;
    if (n >= N) return;

    int r0 = rowptr[n], r1 = r0 + deg[n];
    float a0 = 0.f, a1 = 0.f, a2 = 0.f, a3 = 0.f;
    int j = r0;
    if (r1 - r0 >= 4) {
        // stage 0: descriptors + value loads in flight
        int2 p0 = epack[j], p1 = epack[j + 1], p2 = epack[j + 2], p3 = epack[j + 3];
        float v0 = t2[(size_t)p0.x * F2 + lane];
        float v1 = t2[(size_t)p1.x * F2 + lane];
        float v2 = t2[(size_t)p2.x * F2 + lane];
        float v3 = t2[(size_t)p3.x * F2 + lane];
        j += 4;
        while (j + 4 <= r1) {
            // next group's descriptors + values issue BEFORE consuming current
            int2 q0 = epack[j], q1 = epack[j + 1], q2 = epack[j + 2], q3 = epack[j + 3];
            float w0 = t2[(size_t)q0.x * F2 + lane];
            float w1 = t2[(size_t)q1.x * F2 + lane];
            float w2 = t2[(size_t)q2.x * F2 + lane];
            float w3 = t2[(size_t)q3.x * F2 + lane];
            a0 += __int_as_float(p0.y) * v0;
            a1 += __int_as_float(p1.y) * v1;
            a2 += __int_as_float(p2.y) * v2;
            a3 += __int_as_float(p3.y) * v3;
            p0 = q0; p1 = q1; p2 = q2; p3 = q3;
            v0 = w0; v1 = w1; v2 = w2; v3 = w3;
            j += 4;
        }
        a0 += __int_as_float(p0.y) * v0;
        a1 += __int_as_float(p1.y) * v1;
        a2 += __int_as_float(p2.y) * v2;
        a3 += __int_as_float(p3.y) * v3;
    }
    for (; j < r1; j++) {
        int2 p = epack[j];
        a0 += __int_as_float(p.y) * t2[(size_t)p.x * F2 + lane];
    }
    float acc = (a0 + a1) + (a2 + a3);
    float dn = dis[n];
    float h2 = fmaxf(acc * dn + t2[(size_t)n * F2 + lane] * dn * dn + b2[lane], 0.0f);
    int g = batch[n];
    atomicAdd(&gsum[(size_t)g * F2 + lane], h2);
    if (lane == 0) atomicAdd(&gcnt[g], 1.0f);
}

// ---------------- per-graph MLP head ----------------
__global__ void k_head(const float* __restrict__ gsum, const float* __restrict__ gcnt,
                       const float* __restrict__ Wf1, const float* __restrict__ bf1,
                       const float* __restrict__ Wf2, const float* __restrict__ bf2,
                       const float* __restrict__ Wf3, const float* __restrict__ bf3,
                       float* __restrict__ out, int G) {
    __shared__ float sg[F2];
    __shared__ float sh1[F1];
    __shared__ float sh2[F2];
    int g = blockIdx.x, t = threadIdx.x;
    if (t < F2) {
        float c = fmaxf(gcnt[g], 1.0f);
        sg[t] = gsum[g * F2 + t] / c;
    }
    __syncthreads();
    {
        float a = bf1[t];
#pragma unroll 8
        for (int k = 0; k < F2; k++) a += sg[k] * Wf1[k * F1 + t];
        sh1[t] = fmaxf(a, 0.0f);
    }
    __syncthreads();
    if (t < F2) {
        float a = bf2[t];
#pragma unroll 8
        for (int k = 0; k < F1; k++) a += sh1[k] * Wf2[k * F2 + t];
        sh2[t] = fmaxf(a, 0.0f);
    }
    __syncthreads();
    if (t < F2) {
        float v = sh2[t] * Wf3[t];
        for (int off = 32; off > 0; off >>= 1) v += __shfl_down(v, off, 64);
        if (t == 0) out[g] = v + bf3[0];
    }
}

extern "C" void kernel_launch(void* const* d_in, const int* in_sizes, int n_in,
                              void* d_out, int out_size, void* d_ws, size_t ws_size,
                              hipStream_t stream) {
    const float* x     = (const float*)d_in[0];
    const int*   ei    = (const int*)d_in[1];
    const int*   batch = (const int*)d_in[2];
    const float* W1    = (const float*)d_in[3];
    const float* b1    = (const float*)d_in[4];
    const float* W2    = (const float*)d_in[5];
    const float* b2    = (const float*)d_in[6];
    const float* Wf1   = (const float*)d_in[7];
    const float* bf1   = (const float*)d_in[8];
    const float* Wf2   = (const float*)d_in[9];
    const float* bf2   = (const float*)d_in[10];
    const float* Wf3   = (const float*)d_in[11];
    const float* bf3   = (const float*)d_in[12];
    float* out = (float*)d_out;

    const int N = in_sizes[0] / F0;
    const int E = in_sizes[1] / 2;
    const int G = out_size;
    const int* src = ei;
    const int* dst = ei + E;

    size_t off = 0;
    auto carve = [&](size_t bytes) {
        void* p = (char*)d_ws + off;
        off += (bytes + 255) & ~(size_t)255;
        return p;
    };
    int*   deg    = (int*)  carve((size_t)N * 4);
    int*   rowloc = (int*)  carve((size_t)N * 4);
    int*   rowptr = (int*)  carve((size_t)N * 4);
    int*   cursor = (int*)  carve((size_t)N * 4);
    int*   bsum   = (int*)  carve(256 * 4);
    float* dis    = (float*)carve((size_t)N * 4);
    int2*  epack  = (int2*) carve((size_t)E * 8);
    float* h1     = (float*)carve((size_t)N * F1 * 4);
    float* t2     = (float*)carve((size_t)N * F2 * 4);
    float* gsum   = (float*)carve((size_t)G * (F2 + 1) * 4);
    float* gcnt   = gsum + (size_t)G * F2;
    (void)ws_size; (void)n_in;

    const int NB = (N + 255) / 256;

    hipMemsetAsync(deg,  0, (size_t)N * 4, stream);
    hipMemsetAsync(gsum, 0, (size_t)G * (F2 + 1) * 4, stream);

    k_count  <<<(E + 255) / 256, 256, 0, stream>>>(dst, E, deg);
    k_scanA  <<<NB, 256, 0, stream>>>(deg, rowloc, bsum, N);
    k_scanB  <<<1, 256, 0, stream>>>(bsum, NB);
    k_scanC  <<<NB, 256, 0, stream>>>(rowloc, bsum, deg, rowptr, cursor, dis, N);
    k_scatter<<<(E + 255) / 256, 256, 0, stream>>>(src, dst, dis, cursor, epack, E);
    k_agg1l1 <<<(N + 3) / 4, 256, 0, stream>>>(rowptr, deg, epack, x, dis, W1, b1, h1, N);
    k_l2gemm <<<(N + TN - 1) / TN, 256, 0, stream>>>(h1, W2, t2, N);
    k_agg2pool<<<(N + 3) / 4, 256, 0, stream>>>(rowptr, deg, epack, t2, dis, b2, batch, gsum, gcnt, N);
    k_head   <<<G, F1, 0, stream>>>(gsum, gcnt, Wf1, bf1, Wf2, bf2, Wf3, bf3, out, G);
}